// Round 3
// baseline (658.522 us; speedup 1.0000x reference)
//
#include <hip/hip_runtime.h>
#include <hip/hip_bf16.h>

typedef __bf16 bf16x8 __attribute__((ext_vector_type(8)));
typedef float f32x4 __attribute__((ext_vector_type(4)));
typedef unsigned short u16;

__device__ __forceinline__ u16 f2bf(float f) {
  __bf16 b = (__bf16)f;                 // RNE fptrunc
  return __builtin_bit_cast(u16, b);
}
__device__ __forceinline__ float bf2f(u16 v) {
  unsigned int u = ((unsigned int)v) << 16;
  return __builtin_bit_cast(float, u);
}

// ---------------- fused prep: X cast + W_{q,k,v} cast + W_{qm,km,vm} transpose ----------
struct PrepArgs {
  const float* X; u16* Xb;
  const float* Wsrc[3]; u16* Wdst[3];
  const float* Tsrc[3]; u16* Tdst[3];
};

__global__ void prep(PrepArgs a) {
  __shared__ float t[32][33];
  const int blk = blockIdx.x, tid = threadIdx.x;
  if (blk < 8192) {
    int i = blk * 256 + tid;
    float4 f = reinterpret_cast<const float4*>(a.X)[i];
    ushort4 o;
    o.x = f2bf(f.x); o.y = f2bf(f.y); o.z = f2bf(f.z); o.w = f2bf(f.w);
    reinterpret_cast<ushort4*>(a.Xb)[i] = o;
  } else if (blk < 20480) {
    int r = blk - 8192;
    int z = r >> 12;
    int i = (r & 4095) * 256 + tid;
    float4 f = reinterpret_cast<const float4*>(a.Wsrc[z])[i];
    ushort4 o;
    o.x = f2bf(f.x); o.y = f2bf(f.y); o.z = f2bf(f.z); o.w = f2bf(f.w);
    reinterpret_cast<ushort4*>(a.Wdst[z])[i] = o;
  } else {
    int r = blk - 20480;
    int z = r >> 12;
    int rem = r & 4095;
    int bx = rem & 63, by = rem >> 6;
    const float* src = a.Tsrc[z];
    u16* dst = a.Tdst[z];
    int tx = tid & 31, ty = tid >> 5;
#pragma unroll
    for (int i = 0; i < 4; ++i)
      t[ty + i * 8][tx] = src[(size_t)(by * 32 + ty + i * 8) * 2048 + bx * 32 + tx];
    __syncthreads();
#pragma unroll
    for (int i = 0; i < 4; ++i)
      dst[(size_t)(bx * 32 + ty + i * 8) * 2048 + by * 32 + tx] = f2bf(t[tx][ty + i * 8]);
  }
}

// ---------------- fused post-transpose: Vm slab transpose + W_o transpose+cast ----------
__global__ void post_transpose(const u16* __restrict__ Vm, u16* __restrict__ VT,
                               const float* __restrict__ Wo, u16* __restrict__ WoT) {
  __shared__ u16 ts[32][33];
  __shared__ float tf[32][33];
  const int blk = blockIdx.x, tid = threadIdx.x;
  const int tx = tid & 31, ty = tid >> 5;
  if (blk < 8192) {
    int slab = blk >> 8;
    int rem = blk & 255;
    int bx = rem & 63, by = rem >> 6;
    const u16* s = Vm + (size_t)slab * 2048 * 128;
    u16* d = VT + (size_t)slab * 128 * 2048;
#pragma unroll
    for (int i = 0; i < 4; ++i)
      ts[ty + i * 8][tx] = s[(size_t)(bx * 32 + ty + i * 8) * 128 + by * 32 + tx];
    __syncthreads();
#pragma unroll
    for (int i = 0; i < 4; ++i)
      d[(size_t)(by * 32 + ty + i * 8) * 2048 + bx * 32 + tx] = ts[tx][ty + i * 8];
  } else {
    int rem = blk - 8192;
    int bx = rem & 63, by = rem >> 6;
#pragma unroll
    for (int i = 0; i < 4; ++i)
      tf[ty + i * 8][tx] = Wo[(size_t)(by * 32 + ty + i * 8) * 2048 + bx * 32 + tx];
    __syncthreads();
#pragma unroll
    for (int i = 0; i < 4; ++i)
      WoT[(size_t)(bx * 32 + ty + i * 8) * 2048 + by * 32 + tx] = f2bf(tf[tx][ty + i * 8]);
  }
}

// ---------------- shared GEMM helpers ----------------
struct GemmArgs { const u16* A[3]; const u16* B[3]; void* C[3]; };

#define SBARF() do { __builtin_amdgcn_sched_barrier(0); __builtin_amdgcn_s_barrier(); \
                     __builtin_amdgcn_sched_barrier(0); } while (0)
#define LGKM0() do { asm volatile("s_waitcnt lgkmcnt(0)" ::: "memory"); \
                     __builtin_amdgcn_sched_barrier(0); } while (0)
#define VMC4()  do { asm volatile("s_waitcnt vmcnt(4)" ::: "memory"); \
                     __builtin_amdgcn_sched_barrier(0); } while (0)
#define VMC6()  do { asm volatile("s_waitcnt vmcnt(6)" ::: "memory"); \
                     __builtin_amdgcn_sched_barrier(0); } while (0)
#define VMC0()  do { asm volatile("s_waitcnt vmcnt(0)" ::: "memory"); \
                     __builtin_amdgcn_sched_barrier(0); } while (0)

__device__ __forceinline__ void gll16(const u16* gp, u16* lp) {
  __builtin_amdgcn_global_load_lds((const __attribute__((address_space(1))) void*)gp,
                                   (__attribute__((address_space(3))) void*)lp, 16, 0, 0);
}

#define MQUAD(A0_, A1_, M0_, M1_) do { \
    __builtin_amdgcn_s_setprio(1); \
    _Pragma("unroll") for (int s_ = 0; s_ < 2; ++s_) \
      _Pragma("unroll") for (int nt = 0; nt < 4; ++nt) { \
        acc[M0_][nt] = __builtin_amdgcn_mfma_f32_16x16x32_bf16(A0_[s_], bF[nt][s_], acc[M0_][nt], 0, 0, 0); \
        acc[M1_][nt] = __builtin_amdgcn_mfma_f32_16x16x32_bf16(A1_[s_], bF[nt][s_], acc[M1_][nt], 0, 0, 0); } \
    __builtin_amdgcn_s_setprio(0); \
    __builtin_amdgcn_sched_barrier(0); \
  } while (0)

// ---------------- 256x256 8-phase bf16 MFMA GEMM (R2 kernel, used for weight GEMM) ----
template <bool F32OUT>
__global__ __launch_bounds__(512, 2)
void gemm8(GemmArgs g, int M, int N, int K) {
  (void)M;
  extern __shared__ u16 lds[];
  const u16* A = g.A[blockIdx.z];
  const u16* B = g.B[blockIdx.z];
  const int tid = threadIdx.x;
  const int lane = tid & 63, w = tid >> 6;          // 8 waves
  const int wm = w >> 2, wn = w & 3;                // 2M x 4N wave grid
  const int l15 = lane & 15, quad = lane >> 4;
  const int m0 = blockIdx.y * 256, n0 = blockIdx.x * 256;

  const int srow = tid & 127;
  const int sks8 = (tid >> 7) * 8;
  const int swu = w * 512;

  auto stage = [&](int buf, int mat, int half, int kt) {
    const u16* src = mat ? B : A;
    const size_t g0 = (size_t)((mat ? n0 : m0) + half * 128 + srow) * K
                    + (size_t)kt * 64 + sks8;
    u16* l0 = lds + buf * 32768 + (mat * 2 + half) * 8192 + swu;
    gll16(src + g0, l0);
    gll16(src + g0 + 32, l0 + 4096);
  };

  const int aoff = wm * 8192 + quad * 1024 + l15 * 8;
  const int boff = 16384 + (wn >> 1) * 8192 + quad * 1024 + ((wn & 1) * 64 + l15) * 8;

  const f32x4 zf = {0.f, 0.f, 0.f, 0.f};
  f32x4 acc[8][4];
#pragma unroll
  for (int i = 0; i < 8; ++i)
#pragma unroll
    for (int j = 0; j < 4; ++j) acc[i][j] = zf;

  bf16x8 aP[2][2], aR[6][2], bF[4][2];

#define LDB_ALL8(buf_) do { _Pragma("unroll") for (int nt = 0; nt < 4; ++nt) { \
    const u16* p_ = lds + (buf_) * 32768 + boff + nt * 128; \
    bF[nt][0] = *reinterpret_cast<const bf16x8*>(p_); \
    bF[nt][1] = *reinterpret_cast<const bf16x8*>(p_ + 4096); } } while (0)
#define LDA2_8(buf_) do { _Pragma("unroll") for (int mi = 0; mi < 2; ++mi) { \
    const u16* p_ = lds + (buf_) * 32768 + aoff + mi * 128; \
    aP[mi][0] = *reinterpret_cast<const bf16x8*>(p_); \
    aP[mi][1] = *reinterpret_cast<const bf16x8*>(p_ + 4096); } } while (0)
#define LDA6_8(buf_) do { _Pragma("unroll") for (int mi = 0; mi < 6; ++mi) { \
    const u16* p_ = lds + (buf_) * 32768 + aoff + (mi + 2) * 128; \
    aR[mi][0] = *reinterpret_cast<const bf16x8*>(p_); \
    aR[mi][1] = *reinterpret_cast<const bf16x8*>(p_ + 4096); } } while (0)

  const int NT = K >> 6;
  const int NI = NT >> 1;

  stage(0, 0, 0, 0); stage(0, 0, 1, 0); stage(0, 1, 0, 0); stage(0, 1, 1, 0);
  stage(1, 0, 0, 1); stage(1, 0, 1, 1);
  VMC4();
  SBARF();

  for (int i = 0; i < NI; ++i) {
    const int te = 2 * i, to = te + 1;
    const bool pf = (i + 1 < NI);
    // phase 1
    LDB_ALL8(0); LDA2_8(0);
    stage(1, 1, 0, to);
    SBARF(); LGKM0();
    MQUAD(aP[0], aP[1], 0, 1);
    SBARF();
    // phase 2
    LDA6_8(0);
    stage(1, 1, 1, to);
    SBARF(); LGKM0();
    MQUAD(aR[0], aR[1], 2, 3);
    SBARF();
    // phase 3
    if (pf) stage(0, 0, 0, te + 2);
    SBARF();
    MQUAD(aR[2], aR[3], 4, 5);
    SBARF();
    // phase 4
    if (pf) stage(0, 0, 1, te + 2);
    SBARF();
    MQUAD(aR[4], aR[5], 6, 7);
    if (pf) { VMC4(); } else { VMC0(); }
    SBARF();
    // phase 5
    LDB_ALL8(1); LDA2_8(1);
    if (pf) stage(0, 1, 0, te + 2);
    SBARF(); LGKM0();
    MQUAD(aP[0], aP[1], 0, 1);
    SBARF();
    // phase 6
    LDA6_8(1);
    if (pf) stage(0, 1, 1, te + 2);
    SBARF(); LGKM0();
    MQUAD(aR[0], aR[1], 2, 3);
    SBARF();
    // phase 7
    if (pf) stage(1, 0, 0, to + 2);
    SBARF();
    MQUAD(aR[2], aR[3], 4, 5);
    SBARF();
    // phase 8
    if (pf) stage(1, 0, 1, to + 2);
    SBARF();
    MQUAD(aR[4], aR[5], 6, 7);
    VMC4();
    SBARF();
  }

#pragma unroll
  for (int mt = 0; mt < 8; ++mt)
#pragma unroll
    for (int nt = 0; nt < 4; ++nt)
#pragma unroll
      for (int r = 0; r < 4; ++r) {
        int mrow = m0 + wm * 128 + mt * 16 + quad * 4 + r;
        int ncol = n0 + wn * 64 + nt * 16 + l15;
        if constexpr (F32OUT)
          ((float*)g.C[blockIdx.z])[(size_t)mrow * N + ncol] = acc[mt][nt][r];
        else
          ((u16*)g.C[blockIdx.z])[(size_t)mrow * N + ncol] = f2bf(acc[mt][nt][r]);
      }
#undef LDB_ALL8
#undef LDA2_8
#undef LDA6_8
}

// ---------------- 128x256 triple-buffered 2-phase GEMM (R3, for main + final) --------
// BM=128, BN=256, BK=64; 8 waves (2M x 4N), per-wave output 64x64. LDS: 3 buffers x
// (A [ks8][row128][8] = 16KB + B [ks8][row256][8] = 32KB) = 144 KiB dynamic.
// Per K-tile t (buf = t%3), 2 phases, staging tile t+2 into buf (t+2)%3 (last read
// at tile t-1, >=2 barriers ago -> race-free). 6 loads/tile; end-of-tile vmcnt(6)
// leaves only t+2's loads in flight, guaranteeing t+1's tile has landed.
template <bool F32OUT>
__global__ __launch_bounds__(512, 2)
void gemm128(GemmArgs g, int M, int N, int K) {
  (void)M;
  extern __shared__ u16 lds[];
  const u16* A = g.A[blockIdx.z];
  const u16* B = g.B[blockIdx.z];
  const int tid = threadIdx.x;
  const int lane = tid & 63, w = tid >> 6;          // 8 waves
  const int wm = w >> 2, wn = w & 3;                // 2M x 4N wave grid (64x64 each)
  const int l15 = lane & 15, quad = lane >> 4;
  const int m0 = blockIdx.y * 128, n0 = blockIdx.x * 256;

  // staging: A unit u=j*512+tid -> ks=u>>7, row=u&127; B unit u=j*512+tid -> ks=u>>8, row=u&255
  const int arow = tid & 127, aks = tid >> 7;
  const int brow = tid & 255, bks = tid >> 8;
  const int swu = w * 512;                          // wave-uniform lane-block base (u16)

  auto stageA = [&](int bufo, int kt, int j) {
    const u16* gp = A + (size_t)(m0 + arow) * K + (size_t)kt * 64 + (aks + j * 4) * 8;
    gll16(gp, lds + bufo + j * 4096 + swu);
  };
  auto stageB = [&](int bufo, int kt, int j) {
    const u16* gp = B + (size_t)(n0 + brow) * K + (size_t)kt * 64 + (bks + j * 2) * 8;
    gll16(gp, lds + bufo + 8192 + j * 4096 + swu);
  };

  const int aoff = quad * 1024 + wm * 512 + l15 * 8;           // + mt*128, +4096 for kc=1
  const int boff = 8192 + quad * 2048 + wn * 512 + l15 * 8;    // + nt*128, +8192 for kc=1

  const f32x4 zf = {0.f, 0.f, 0.f, 0.f};
  f32x4 acc[4][4];
#pragma unroll
  for (int i = 0; i < 4; ++i)
#pragma unroll
    for (int j = 0; j < 4; ++j) acc[i][j] = zf;

  bf16x8 aP[2][2], aR[2][2], bF[4][2];

#define LDB_ALLT(bo_) do { _Pragma("unroll") for (int nt = 0; nt < 4; ++nt) { \
    const u16* p_ = lds + (bo_) + boff + nt * 128; \
    bF[nt][0] = *reinterpret_cast<const bf16x8*>(p_); \
    bF[nt][1] = *reinterpret_cast<const bf16x8*>(p_ + 8192); } } while (0)
#define LDA01T(bo_) do { _Pragma("unroll") for (int mi = 0; mi < 2; ++mi) { \
    const u16* p_ = lds + (bo_) + aoff + mi * 128; \
    aP[mi][0] = *reinterpret_cast<const bf16x8*>(p_); \
    aP[mi][1] = *reinterpret_cast<const bf16x8*>(p_ + 4096); } } while (0)
#define LDA23T(bo_) do { _Pragma("unroll") for (int mi = 0; mi < 2; ++mi) { \
    const u16* p_ = lds + (bo_) + aoff + (mi + 2) * 128; \
    aR[mi][0] = *reinterpret_cast<const bf16x8*>(p_); \
    aR[mi][1] = *reinterpret_cast<const bf16x8*>(p_ + 4096); } } while (0)

  const int NT = K >> 6;   // >= 2 for all our shapes

  // prologue: tile0 -> buf0, tile1 -> buf1
#pragma unroll
  for (int j = 0; j < 4; ++j) stageB(0, 0, j);
#pragma unroll
  for (int j = 0; j < 2; ++j) stageA(0, 0, j);
#pragma unroll
  for (int j = 0; j < 4; ++j) stageB(24576, 1, j);
#pragma unroll
  for (int j = 0; j < 2; ++j) stageA(24576, 1, j);
  VMC6();
  SBARF();

  int bo = 0, bo2 = 49152;            // buf(t)%3 * 24576, buf(t+2)%3 * 24576
  for (int t = 0; t < NT; ++t) {
    const bool pf = (t + 2 < NT);
    // phase 1: read B(all) + A(m0,m1) of buf t; stage half of tile t+2; MFMA m0,m1
    LDB_ALLT(bo); LDA01T(bo);
    if (pf) { stageB(bo2, t + 2, 0); stageB(bo2, t + 2, 1); stageA(bo2, t + 2, 0); }
    SBARF(); LGKM0();
    MQUAD(aP[0], aP[1], 0, 1);
    SBARF();
    // phase 2: read A(m2,m3); stage rest of tile t+2; MFMA m2,m3
    LDA23T(bo);
    if (pf) { stageB(bo2, t + 2, 2); stageB(bo2, t + 2, 3); stageA(bo2, t + 2, 1); }
    SBARF(); LGKM0();
    MQUAD(aR[0], aR[1], 2, 3);
    if (pf) { VMC6(); } else { VMC0(); }
    SBARF();
    bo = (bo == 49152) ? 0 : bo + 24576;
    bo2 = (bo2 == 49152) ? 0 : bo2 + 24576;
  }

  // epilogue: per-wave 64x64 tile at (m0+wm*64, n0+wn*64)
#pragma unroll
  for (int mt = 0; mt < 4; ++mt)
#pragma unroll
    for (int nt = 0; nt < 4; ++nt)
#pragma unroll
      for (int r = 0; r < 4; ++r) {
        int mrow = m0 + wm * 64 + mt * 16 + quad * 4 + r;
        int ncol = n0 + wn * 64 + nt * 16 + l15;
        if constexpr (F32OUT)
          ((float*)g.C[blockIdx.z])[(size_t)mrow * N + ncol] = acc[mt][nt][r];
        else
          ((u16*)g.C[blockIdx.z])[(size_t)mrow * N + ncol] = f2bf(acc[mt][nt][r]);
      }
#undef LDB_ALLT
#undef LDA01T
#undef LDA23T
}

// ---------------- flash attention (unchanged): no-max softmax, KC=64, 32q/wave -------
__global__ __launch_bounds__(256, 2)
void flash_attn(const u16* __restrict__ Qm, const u16* __restrict__ Km,
                const u16* __restrict__ VTr, const int* __restrict__ mask,
                u16* __restrict__ Out) {
  __shared__ __align__(16) u16 Ks[16 * 64 * 8];
  __shared__ __align__(16) u16 Vs[8 * 128 * 8];
  __shared__ __align__(16) u16 PL[4][32 * 64];
  __shared__ u16 Mf[2048];

  const int b = blockIdx.z, head = blockIdx.y, qb = blockIdx.x;
  const int slab = b * 16 + head;
  const u16* Qs = Qm + (size_t)slab * 2048 * 128;
  const u16* Kg = Km + (size_t)slab * 2048 * 128;
  const u16* Vg = VTr + (size_t)slab * 128 * 2048;
  u16* Og = Out + (size_t)slab * 2048 * 128;
  const int* mb = mask + b * 2048;

  const int tid = threadIdx.x;
  const int lane = tid & 63, w = tid >> 6;
  const int l15 = lane & 15, quad = lane >> 4;
  const int q0w = qb * 128 + w * 32;

#pragma unroll
  for (int j = 0; j < 8; ++j) {
    int i = j * 256 + tid;
    Mf[i] = mb[i] ? (u16)0x3F80 : (u16)0;
  }

  bf16x8 aQ[2][4];
#pragma unroll
  for (int mt = 0; mt < 2; ++mt)
#pragma unroll
    for (int c = 0; c < 4; ++c)
      aQ[mt][c] = *reinterpret_cast<const bf16x8*>(
          Qs + (size_t)(q0w + mt * 16 + l15) * 128 + c * 32 + quad * 8);

  int mq[2][4];
#pragma unroll
  for (int mt = 0; mt < 2; ++mt)
#pragma unroll
    for (int r = 0; r < 4; ++r) mq[mt][r] = mb[q0w + mt * 16 + quad * 4 + r];

  const f32x4 zf = {0.f, 0.f, 0.f, 0.f};
  float l_part[2][4];
  f32x4 acc[2][8];
#pragma unroll
  for (int mt = 0; mt < 2; ++mt) {
#pragma unroll
    for (int r = 0; r < 4; ++r) l_part[mt][r] = 0.f;
#pragma unroll
    for (int nd = 0; nd < 8; ++nd) acc[mt][nd] = zf;
  }

  __syncthreads();

  u16* PLw = PL[w];

  for (int k0 = 0; k0 < 2048; k0 += 64) {
#pragma unroll
    for (int t = 0; t < 8; ++t) {
      int idx = w * 8 + t;
      if (idx < 16) {
        const u16* gp = Kg + (size_t)(k0 + lane) * 128 + idx * 8;
        u16* lp = Ks + idx * 64 * 8;
        __builtin_amdgcn_global_load_lds((const __attribute__((address_space(1))) void*)gp,
                                         (__attribute__((address_space(3))) void*)lp,
                                         16, 0, 0);
      } else {
        int u = idx - 16, kc = u >> 1, dh = u & 1;
        const u16* gp = Vg + (size_t)(dh * 64 + lane) * 2048 + k0 + kc * 8;
        u16* lp = Vs + (kc * 128 + dh * 64) * 8;
        __builtin_amdgcn_global_load_lds((const __attribute__((address_space(1))) void*)gp,
                                         (__attribute__((address_space(3))) void*)lp,
                                         16, 0, 0);
      }
    }
    __syncthreads();

    f32x4 st[2][4];
#pragma unroll
    for (int mt = 0; mt < 2; ++mt)
#pragma unroll
      for (int nt = 0; nt < 4; ++nt) st[mt][nt] = zf;
#pragma unroll
    for (int c = 0; c < 4; ++c)
#pragma unroll
      for (int nt = 0; nt < 4; ++nt) {
        bf16x8 bK = *reinterpret_cast<const bf16x8*>(
            &Ks[((c * 4 + quad) * 64 + nt * 16 + l15) * 8]);
        st[0][nt] = __builtin_amdgcn_mfma_f32_16x16x32_bf16(aQ[0][c], bK, st[0][nt], 0, 0, 0);
        st[1][nt] = __builtin_amdgcn_mfma_f32_16x16x32_bf16(aQ[1][c], bK, st[1][nt], 0, 0, 0);
      }

    float mkf[4];
#pragma unroll
    for (int nt = 0; nt < 4; ++nt) mkf[nt] = bf2f(Mf[k0 + nt * 16 + l15]);

#pragma unroll
    for (int mt = 0; mt < 2; ++mt)
#pragma unroll
      for (int nt = 0; nt < 4; ++nt)
#pragma unroll
        for (int r = 0; r < 4; ++r) {
          float e = __expf(st[mt][nt][r]) * mkf[nt];
          float p = mq[mt][r] ? e : 1.0f;
          l_part[mt][r] += p;
          int row = mt * 16 + quad * 4 + r;
          int col = nt * 16 + l15;
          int addr = row * 64 + (((col >> 3) ^ (row & 7)) << 3) + (col & 7);
          PLw[addr] = f2bf(p);
        }

#pragma unroll
    for (int pc = 0; pc < 2; ++pc) {
      bf16x8 aP0 = *reinterpret_cast<const bf16x8*>(
          &PLw[(0 + l15) * 64 + (((pc * 4 + quad) ^ (l15 & 7)) << 3)]);
      bf16x8 aP1 = *reinterpret_cast<const bf16x8*>(
          &PLw[(16 + l15) * 64 + (((pc * 4 + quad) ^ (l15 & 7)) << 3)]);
#pragma unroll
      for (int nd = 0; nd < 8; ++nd) {
        bf16x8 bV = *reinterpret_cast<const bf16x8*>(
            &Vs[((pc * 4 + quad) * 128 + nd * 16 + l15) * 8]);
        acc[0][nd] = __builtin_amdgcn_mfma_f32_16x16x32_bf16(aP0, bV, acc[0][nd], 0, 0, 0);
        acc[1][nd] = __builtin_amdgcn_mfma_f32_16x16x32_bf16(aP1, bV, acc[1][nd], 0, 0, 0);
      }
    }
    __syncthreads();
  }

  float inv[2][4];
#pragma unroll
  for (int mt = 0; mt < 2; ++mt)
#pragma unroll
    for (int r = 0; r < 4; ++r) {
      float l = l_part[mt][r];
      l += __shfl_xor(l, 1, 16);
      l += __shfl_xor(l, 2, 16);
      l += __shfl_xor(l, 4, 16);
      l += __shfl_xor(l, 8, 16);
      inv[mt][r] = 1.0f / l;
    }
#pragma unroll
  for (int mt = 0; mt < 2; ++mt)
#pragma unroll
    for (int nd = 0; nd < 8; ++nd)
#pragma unroll
      for (int r = 0; r < 4; ++r)
        Og[(size_t)(q0w + mt * 16 + quad * 4 + r) * 128 + nd * 16 + l15] =
            f2bf(acc[mt][nd][r] * inv[mt][r]);
}

// ---------------- launcher ----------------
extern "C" void kernel_launch(void* const* d_in, const int* in_sizes, int n_in,
                              void* d_out, int out_size, void* d_ws, size_t ws_size,
                              hipStream_t stream) {
  const float* X    = (const float*)d_in[0];
  const int*   mask = (const int*)d_in[1];
  const float* W_q  = (const float*)d_in[2];
  const float* W_k  = (const float*)d_in[3];
  const float* W_v  = (const float*)d_in[4];
  const float* W_qm = (const float*)d_in[5];
  const float* W_km = (const float*)d_in[6];
  const float* W_vm = (const float*)d_in[7];
  const float* W_o  = (const float*)d_in[8];
  float* out = (float*)d_out;

  char* ws = (char*)d_ws;
  const size_t MB = 1ull << 20;
  u16* Xb    = (u16*)(ws);
  u16* Wc0   = (u16*)(ws + 16 * MB);
  u16* Wc1   = (u16*)(ws + 24 * MB);
  u16* Wc2   = (u16*)(ws + 32 * MB);
  u16* WmT0  = (u16*)(ws + 40 * MB);
  u16* WmT1  = (u16*)(ws + 48 * MB);
  u16* WmT2  = (u16*)(ws + 56 * MB);
  u16* WqqT0 = (u16*)(ws + 64 * MB);
  u16* WqqT1 = (u16*)(ws + 72 * MB);
  u16* WqqT2 = (u16*)(ws + 80 * MB);
  u16* Qm    = (u16*)(ws + 88 * MB);
  u16* Km    = (u16*)(ws + 104 * MB);
  u16* Vm    = (u16*)(ws + 120 * MB);
  u16* VT    = Wc0;
  u16* AO    = WmT0;
  u16* WoT   = WqqT0;

  static bool attr_done = false;
  if (!attr_done) {
    (void)hipFuncSetAttribute(reinterpret_cast<const void*>(&gemm8<false>),
                              hipFuncAttributeMaxDynamicSharedMemorySize, 131072);
    (void)hipFuncSetAttribute(reinterpret_cast<const void*>(&gemm8<true>),
                              hipFuncAttributeMaxDynamicSharedMemorySize, 131072);
    (void)hipFuncSetAttribute(reinterpret_cast<const void*>(&gemm128<false>),
                              hipFuncAttributeMaxDynamicSharedMemorySize, 147456);
    (void)hipFuncSetAttribute(reinterpret_cast<const void*>(&gemm128<true>),
                              hipFuncAttributeMaxDynamicSharedMemorySize, 147456);
    attr_done = true;
  }

  // fused prep: X cast, W_{q,k,v} cast, W_{qm,km,vm} transpose
  {
    PrepArgs a;
    a.X = X; a.Xb = Xb;
    a.Wsrc[0] = W_q;  a.Wsrc[1] = W_k;  a.Wsrc[2] = W_v;
    a.Wdst[0] = Wc0;  a.Wdst[1] = Wc1;  a.Wdst[2] = Wc2;
    a.Tsrc[0] = W_qm; a.Tsrc[1] = W_km; a.Tsrc[2] = W_vm;
    a.Tdst[0] = WmT0; a.Tdst[1] = WmT1; a.Tdst[2] = WmT2;
    prep<<<dim3(32768), dim3(256), 0, stream>>>(a);
  }

  // fused weights: WqqT[n][k] = (W_q @ W_qm)^T = WmT . Wc^T   (2048^3, z=3; 192 blocks)
  {
    GemmArgs g{{WmT0, WmT1, WmT2}, {Wc0, Wc1, Wc2}, {WqqT0, WqqT1, WqqT2}};
    gemm8<false><<<dim3(8, 8, 3), dim3(512), 131072, stream>>>(g, 2048, 2048, 2048);
  }

  // {Qm,Km,Vm} = Xb . WqqT^T   (4096x2048x2048, z=3; 768 blocks = 3 exact rounds)
  {
    GemmArgs g{{Xb, Xb, Xb}, {WqqT0, WqqT1, WqqT2}, {Qm, Km, Vm}};
    gemm128<false><<<dim3(8, 32, 3), dim3(512), 147456, stream>>>(g, 4096, 2048, 2048);
  }

  // fused: Vm slab transpose -> VT, W_o transpose -> WoT
  post_transpose<<<dim3(12288), dim3(256), 0, stream>>>(Vm, VT, W_o, WoT);

  flash_attn<<<dim3(16, 16, 2), dim3(256), 0, stream>>>(Qm, Km, VT, mask, AO);

  // out = AO . WoT^T   (4096x2048x2048; 256 blocks = 1 exact full round)
  {
    GemmArgs g{{AO, AO, AO}, {WoT, WoT, WoT}, {out, out, out}};
    gemm128<true><<<dim3(8, 32, 1), dim3(512), 147456, stream>>>(g, 4096, 2048, 2048);
  }
}

// Round 4
// 550.955 us; speedup vs baseline: 1.1952x; 1.1952x over previous
//
#include <hip/hip_runtime.h>
#include <hip/hip_bf16.h>

typedef __bf16 bf16x8 __attribute__((ext_vector_type(8)));
typedef float f32x4 __attribute__((ext_vector_type(4)));
typedef unsigned short u16;

__device__ __forceinline__ u16 f2bf(float f) {
  __bf16 b = (__bf16)f;                 // RNE fptrunc
  return __builtin_bit_cast(u16, b);
}
__device__ __forceinline__ float bf2f(u16 v) {
  unsigned int u = ((unsigned int)v) << 16;
  return __builtin_bit_cast(float, u);
}

// ---------------- fused prep: X cast + W_{q,k,v} cast + W_{qm,km,vm} transpose ----------
struct PrepArgs {
  const float* X; u16* Xb;
  const float* Wsrc[3]; u16* Wdst[3];
  const float* Tsrc[3]; u16* Tdst[3];
};

__global__ void prep(PrepArgs a) {
  __shared__ float t[32][33];
  const int blk = blockIdx.x, tid = threadIdx.x;
  if (blk < 8192) {
    int i = blk * 256 + tid;
    float4 f = reinterpret_cast<const float4*>(a.X)[i];
    ushort4 o;
    o.x = f2bf(f.x); o.y = f2bf(f.y); o.z = f2bf(f.z); o.w = f2bf(f.w);
    reinterpret_cast<ushort4*>(a.Xb)[i] = o;
  } else if (blk < 20480) {
    int r = blk - 8192;
    int z = r >> 12;
    int i = (r & 4095) * 256 + tid;
    float4 f = reinterpret_cast<const float4*>(a.Wsrc[z])[i];
    ushort4 o;
    o.x = f2bf(f.x); o.y = f2bf(f.y); o.z = f2bf(f.z); o.w = f2bf(f.w);
    reinterpret_cast<ushort4*>(a.Wdst[z])[i] = o;
  } else {
    int r = blk - 20480;
    int z = r >> 12;
    int rem = r & 4095;
    int bx = rem & 63, by = rem >> 6;
    const float* src = a.Tsrc[z];
    u16* dst = a.Tdst[z];
    int tx = tid & 31, ty = tid >> 5;
#pragma unroll
    for (int i = 0; i < 4; ++i)
      t[ty + i * 8][tx] = src[(size_t)(by * 32 + ty + i * 8) * 2048 + bx * 32 + tx];
    __syncthreads();
#pragma unroll
    for (int i = 0; i < 4; ++i)
      dst[(size_t)(bx * 32 + ty + i * 8) * 2048 + by * 32 + tx] = f2bf(t[tx][ty + i * 8]);
  }
}

// ---------------- fused post-transpose: Vm slab transpose + W_o transpose+cast ----------
__global__ void post_transpose(const u16* __restrict__ Vm, u16* __restrict__ VT,
                               const float* __restrict__ Wo, u16* __restrict__ WoT) {
  __shared__ u16 ts[32][33];
  __shared__ float tf[32][33];
  const int blk = blockIdx.x, tid = threadIdx.x;
  const int tx = tid & 31, ty = tid >> 5;
  if (blk < 8192) {
    int slab = blk >> 8;
    int rem = blk & 255;
    int bx = rem & 63, by = rem >> 6;
    const u16* s = Vm + (size_t)slab * 2048 * 128;
    u16* d = VT + (size_t)slab * 128 * 2048;
#pragma unroll
    for (int i = 0; i < 4; ++i)
      ts[ty + i * 8][tx] = s[(size_t)(bx * 32 + ty + i * 8) * 128 + by * 32 + tx];
    __syncthreads();
#pragma unroll
    for (int i = 0; i < 4; ++i)
      d[(size_t)(by * 32 + ty + i * 8) * 2048 + bx * 32 + tx] = ts[tx][ty + i * 8];
  } else {
    int rem = blk - 8192;
    int bx = rem & 63, by = rem >> 6;
#pragma unroll
    for (int i = 0; i < 4; ++i)
      tf[ty + i * 8][tx] = Wo[(size_t)(by * 32 + ty + i * 8) * 2048 + bx * 32 + tx];
    __syncthreads();
#pragma unroll
    for (int i = 0; i < 4; ++i)
      WoT[(size_t)(bx * 32 + ty + i * 8) * 2048 + by * 32 + tx] = f2bf(tf[tx][ty + i * 8]);
  }
}

// ---------------- shared GEMM helpers ----------------
struct GemmArgs { const u16* A[3]; const u16* B[3]; void* C[3]; };

#define SBARF() do { __builtin_amdgcn_sched_barrier(0); __builtin_amdgcn_s_barrier(); \
                     __builtin_amdgcn_sched_barrier(0); } while (0)
#define LGKM0() do { asm volatile("s_waitcnt lgkmcnt(0)" ::: "memory"); \
                     __builtin_amdgcn_sched_barrier(0); } while (0)
#define VMC4()  do { asm volatile("s_waitcnt vmcnt(4)" ::: "memory"); \
                     __builtin_amdgcn_sched_barrier(0); } while (0)
#define VMC0()  do { asm volatile("s_waitcnt vmcnt(0)" ::: "memory"); \
                     __builtin_amdgcn_sched_barrier(0); } while (0)

__device__ __forceinline__ void gll16(const u16* gp, u16* lp) {
  __builtin_amdgcn_global_load_lds((const __attribute__((address_space(1))) void*)gp,
                                   (__attribute__((address_space(3))) void*)lp, 16, 0, 0);
}

#define MQUAD(A0_, A1_, M0_, M1_) do { \
    __builtin_amdgcn_s_setprio(1); \
    _Pragma("unroll") for (int s_ = 0; s_ < 2; ++s_) \
      _Pragma("unroll") for (int nt = 0; nt < 4; ++nt) { \
        acc[M0_][nt] = __builtin_amdgcn_mfma_f32_16x16x32_bf16(A0_[s_], bF[nt][s_], acc[M0_][nt], 0, 0, 0); \
        acc[M1_][nt] = __builtin_amdgcn_mfma_f32_16x16x32_bf16(A1_[s_], bF[nt][s_], acc[M1_][nt], 0, 0, 0); } \
    __builtin_amdgcn_s_setprio(0); \
    __builtin_amdgcn_sched_barrier(0); \
  } while (0)

// ---------------- 256x256 8-phase bf16 MFMA GEMM (R2 kernel, all GEMMs) ---------------
template <bool F32OUT>
__global__ __launch_bounds__(512, 2)
void gemm8(GemmArgs g, int M, int N, int K) {
  (void)M;
  extern __shared__ u16 lds[];
  const u16* A = g.A[blockIdx.z];
  const u16* B = g.B[blockIdx.z];
  const int tid = threadIdx.x;
  const int lane = tid & 63, w = tid >> 6;          // 8 waves
  const int wm = w >> 2, wn = w & 3;                // 2M x 4N wave grid
  const int l15 = lane & 15, quad = lane >> 4;
  const int m0 = blockIdx.y * 256, n0 = blockIdx.x * 256;

  const int srow = tid & 127;
  const int sks8 = (tid >> 7) * 8;
  const int swu = w * 512;

  auto stage = [&](int buf, int mat, int half, int kt) {
    const u16* src = mat ? B : A;
    const size_t g0 = (size_t)((mat ? n0 : m0) + half * 128 + srow) * K
                    + (size_t)kt * 64 + sks8;
    u16* l0 = lds + buf * 32768 + (mat * 2 + half) * 8192 + swu;
    gll16(src + g0, l0);
    gll16(src + g0 + 32, l0 + 4096);
  };

  const int aoff = wm * 8192 + quad * 1024 + l15 * 8;
  const int boff = 16384 + (wn >> 1) * 8192 + quad * 1024 + ((wn & 1) * 64 + l15) * 8;

  const f32x4 zf = {0.f, 0.f, 0.f, 0.f};
  f32x4 acc[8][4];
#pragma unroll
  for (int i = 0; i < 8; ++i)
#pragma unroll
    for (int j = 0; j < 4; ++j) acc[i][j] = zf;

  bf16x8 aP[2][2], aR[6][2], bF[4][2];

#define LDB_ALL8(buf_) do { _Pragma("unroll") for (int nt = 0; nt < 4; ++nt) { \
    const u16* p_ = lds + (buf_) * 32768 + boff + nt * 128; \
    bF[nt][0] = *reinterpret_cast<const bf16x8*>(p_); \
    bF[nt][1] = *reinterpret_cast<const bf16x8*>(p_ + 4096); } } while (0)
#define LDA2_8(buf_) do { _Pragma("unroll") for (int mi = 0; mi < 2; ++mi) { \
    const u16* p_ = lds + (buf_) * 32768 + aoff + mi * 128; \
    aP[mi][0] = *reinterpret_cast<const bf16x8*>(p_); \
    aP[mi][1] = *reinterpret_cast<const bf16x8*>(p_ + 4096); } } while (0)
#define LDA6_8(buf_) do { _Pragma("unroll") for (int mi = 0; mi < 6; ++mi) { \
    const u16* p_ = lds + (buf_) * 32768 + aoff + (mi + 2) * 128; \
    aR[mi][0] = *reinterpret_cast<const bf16x8*>(p_); \
    aR[mi][1] = *reinterpret_cast<const bf16x8*>(p_ + 4096); } } while (0)

  const int NT = K >> 6;
  const int NI = NT >> 1;

  stage(0, 0, 0, 0); stage(0, 0, 1, 0); stage(0, 1, 0, 0); stage(0, 1, 1, 0);
  stage(1, 0, 0, 1); stage(1, 0, 1, 1);
  VMC4();
  SBARF();

  for (int i = 0; i < NI; ++i) {
    const int te = 2 * i, to = te + 1;
    const bool pf = (i + 1 < NI);
    // phase 1
    LDB_ALL8(0); LDA2_8(0);
    stage(1, 1, 0, to);
    SBARF(); LGKM0();
    MQUAD(aP[0], aP[1], 0, 1);
    SBARF();
    // phase 2
    LDA6_8(0);
    stage(1, 1, 1, to);
    SBARF(); LGKM0();
    MQUAD(aR[0], aR[1], 2, 3);
    SBARF();
    // phase 3
    if (pf) stage(0, 0, 0, te + 2);
    SBARF();
    MQUAD(aR[2], aR[3], 4, 5);
    SBARF();
    // phase 4
    if (pf) stage(0, 0, 1, te + 2);
    SBARF();
    MQUAD(aR[4], aR[5], 6, 7);
    if (pf) { VMC4(); } else { VMC0(); }
    SBARF();
    // phase 5
    LDB_ALL8(1); LDA2_8(1);
    if (pf) stage(0, 1, 0, te + 2);
    SBARF(); LGKM0();
    MQUAD(aP[0], aP[1], 0, 1);
    SBARF();
    // phase 6
    LDA6_8(1);
    if (pf) stage(0, 1, 1, te + 2);
    SBARF(); LGKM0();
    MQUAD(aR[0], aR[1], 2, 3);
    SBARF();
    // phase 7
    if (pf) stage(1, 0, 0, to + 2);
    SBARF();
    MQUAD(aR[2], aR[3], 4, 5);
    SBARF();
    // phase 8
    if (pf) stage(1, 0, 1, to + 2);
    SBARF();
    MQUAD(aR[4], aR[5], 6, 7);
    VMC4();
    SBARF();
  }

#pragma unroll
  for (int mt = 0; mt < 8; ++mt)
#pragma unroll
    for (int nt = 0; nt < 4; ++nt)
#pragma unroll
      for (int r = 0; r < 4; ++r) {
        int mrow = m0 + wm * 128 + mt * 16 + quad * 4 + r;
        int ncol = n0 + wn * 64 + nt * 16 + l15;
        if constexpr (F32OUT)
          ((float*)g.C[blockIdx.z])[(size_t)mrow * N + ncol] = acc[mt][nt][r];
        else
          ((u16*)g.C[blockIdx.z])[(size_t)mrow * N + ncol] = f2bf(acc[mt][nt][r]);
      }
#undef LDB_ALL8
#undef LDA2_8
#undef LDA6_8
}

// ---------------- flash attention R4: 8 waves, dbuf K/V, 1 barrier/tile ---------------
// grid (8 qblocks, 16 heads, 2 batch) = 256 blocks (exact 1/CU), block 512 = 8 waves
// x 32 q-rows = 256 q/block. Dynamic LDS 100 KiB:
//   Ks[buf] @ buf*8192        [dchunk16][kk64][8]   16 KB each
//   Vs[buf] @ 16384+buf*8192  [kchunk8][d128][8]    16 KB each
//   PL      @ 32768+w*2048    per-wave P 32x64 XOR-swizzled
//   Mf      @ 49152           bf16 k-mask multiplier
// Per tile t (buf c=t&1): stage tile t+1 into buf c^1 (its last reads finished before
// the barrier ending tile t-1) -> QK (ds_read Ks[c]) -> softmax -> PV (PL+Vs[c]) ->
// VMC0 (own 4 stage loads; latency hidden under ~2000cy compute) -> barrier.
__global__ __launch_bounds__(512, 2)
void flash_attn(const u16* __restrict__ Qm, const u16* __restrict__ Km,
                const u16* __restrict__ VTr, const int* __restrict__ mask,
                u16* __restrict__ Out) {
  extern __shared__ u16 lds[];
  const int b = blockIdx.z, head = blockIdx.y, qb = blockIdx.x;
  const int slab = b * 16 + head;
  const u16* Qs = Qm + (size_t)slab * 2048 * 128;
  const u16* Kg = Km + (size_t)slab * 2048 * 128;
  const u16* Vg = VTr + (size_t)slab * 128 * 2048;
  u16* Og = Out + (size_t)slab * 2048 * 128;
  const int* mb = mask + b * 2048;

  const int tid = threadIdx.x;
  const int lane = tid & 63, w = tid >> 6;          // 8 waves
  const int l15 = lane & 15, quad = lane >> 4;
  const int q0w = qb * 256 + w * 32;

  u16* Mf = lds + 49152;
  u16* PLw = lds + 32768 + w * 2048;

  // stage bf16 k-mask into LDS (once)
#pragma unroll
  for (int j = 0; j < 4; ++j) {
    int i = j * 512 + tid;
    Mf[i] = mb[i] ? (u16)0x3F80 : (u16)0;
  }

  // Q fragments for 2 m-tiles: A[m=lane&15][k=quad*8+j]
  bf16x8 aQ[2][4];
#pragma unroll
  for (int mt = 0; mt < 2; ++mt)
#pragma unroll
    for (int c = 0; c < 4; ++c)
      aQ[mt][c] = *reinterpret_cast<const bf16x8*>(
          Qs + (size_t)(q0w + mt * 16 + l15) * 128 + c * 32 + quad * 8);

  int mq[2][4];
#pragma unroll
  for (int mt = 0; mt < 2; ++mt)
#pragma unroll
    for (int r = 0; r < 4; ++r) mq[mt][r] = mb[q0w + mt * 16 + quad * 4 + r];

  // stage K/V tile into buffer: 4 gll16 per wave (waves 0-3: K, waves 4-7: V)
  auto stageKV = [&](int buf, int k0) {
#pragma unroll
    for (int t = 0; t < 4; ++t) {
      int idx = w * 4 + t;              // 0..31 (wave-uniform)
      if (idx < 16) {                   // K: dchunk = idx
        const u16* gp = Kg + (size_t)(k0 + lane) * 128 + idx * 8;
        gll16(gp, lds + buf * 8192 + idx * 512);
      } else {                          // V: kchunk = (idx-16)>>1, d-half = (idx-16)&1
        int u = idx - 16, kc = u >> 1, dh = u & 1;
        const u16* gp = Vg + (size_t)(dh * 64 + lane) * 2048 + k0 + kc * 8;
        gll16(gp, lds + 16384 + buf * 8192 + (kc * 128 + dh * 64) * 8);
      }
    }
  };

  const f32x4 zf = {0.f, 0.f, 0.f, 0.f};
  float l_part[2][4];
  f32x4 acc[2][8];
#pragma unroll
  for (int mt = 0; mt < 2; ++mt) {
#pragma unroll
    for (int r = 0; r < 4; ++r) l_part[mt][r] = 0.f;
#pragma unroll
    for (int nd = 0; nd < 8; ++nd) acc[mt][nd] = zf;
  }

  // prologue: tile 0 -> buf 0; full drain covers Mf writes + stage loads
  stageKV(0, 0);
  __syncthreads();

  for (int t = 0; t < 32; ++t) {
    const int cur = t & 1;
    const int k0 = t * 64;
    if (t + 1 < 32) stageKV(cur ^ 1, k0 + 64);     // prefetch next tile

    const u16* Ks = lds + cur * 8192;
    const u16* Vs = lds + 16384 + cur * 8192;

    // S[32q x 64k] = Q . K^T
    f32x4 st[2][4];
#pragma unroll
    for (int mt = 0; mt < 2; ++mt)
#pragma unroll
      for (int nt = 0; nt < 4; ++nt) st[mt][nt] = zf;
#pragma unroll
    for (int c = 0; c < 4; ++c)
#pragma unroll
      for (int nt = 0; nt < 4; ++nt) {
        bf16x8 bK = *reinterpret_cast<const bf16x8*>(
            &Ks[((c * 4 + quad) * 64 + nt * 16 + l15) * 8]);
        st[0][nt] = __builtin_amdgcn_mfma_f32_16x16x32_bf16(aQ[0][c], bK, st[0][nt], 0, 0, 0);
        st[1][nt] = __builtin_amdgcn_mfma_f32_16x16x32_bf16(aQ[1][c], bK, st[1][nt], 0, 0, 0);
      }

    // no-max softmax: p = mq ? exp(s)*mk : 1   (exact vs reference semantics)
    float mkf[4];
#pragma unroll
    for (int nt = 0; nt < 4; ++nt) mkf[nt] = bf2f(Mf[k0 + nt * 16 + l15]);

#pragma unroll
    for (int mt = 0; mt < 2; ++mt)
#pragma unroll
      for (int nt = 0; nt < 4; ++nt)
#pragma unroll
        for (int r = 0; r < 4; ++r) {
          float e = __expf(st[mt][nt][r]) * mkf[nt];
          float p = mq[mt][r] ? e : 1.0f;
          l_part[mt][r] += p;
          int row = mt * 16 + quad * 4 + r;
          int col = nt * 16 + l15;
          int addr = row * 64 + (((col >> 3) ^ (row & 7)) << 3) + (col & 7);
          PLw[addr] = f2bf(p);
        }

    // O += P . V   (per-wave LDS round trip for P, in-order within wave)
#pragma unroll
    for (int pc = 0; pc < 2; ++pc) {
      bf16x8 aP0 = *reinterpret_cast<const bf16x8*>(
          &PLw[(0 + l15) * 64 + (((pc * 4 + quad) ^ (l15 & 7)) << 3)]);
      bf16x8 aP1 = *reinterpret_cast<const bf16x8*>(
          &PLw[(16 + l15) * 64 + (((pc * 4 + quad) ^ (l15 & 7)) << 3)]);
#pragma unroll
      for (int nd = 0; nd < 8; ++nd) {
        bf16x8 bV = *reinterpret_cast<const bf16x8*>(
            &Vs[((pc * 4 + quad) * 128 + nd * 16 + l15) * 8]);
        acc[0][nd] = __builtin_amdgcn_mfma_f32_16x16x32_bf16(aP0, bV, acc[0][nd], 0, 0, 0);
        acc[1][nd] = __builtin_amdgcn_mfma_f32_16x16x32_bf16(aP1, bV, acc[1][nd], 0, 0, 0);
      }
    }

    VMC0();          // own stage loads landed (hidden under compute)
    SBARF();         // publish: next iter may read buf cur^1 and overwrite buf cur
  }

  // final row-sum reduce over lane&15, then normalize + store
  float inv[2][4];
#pragma unroll
  for (int mt = 0; mt < 2; ++mt)
#pragma unroll
    for (int r = 0; r < 4; ++r) {
      float l = l_part[mt][r];
      l += __shfl_xor(l, 1, 16);
      l += __shfl_xor(l, 2, 16);
      l += __shfl_xor(l, 4, 16);
      l += __shfl_xor(l, 8, 16);
      inv[mt][r] = 1.0f / l;
    }
#pragma unroll
  for (int mt = 0; mt < 2; ++mt)
#pragma unroll
    for (int nd = 0; nd < 8; ++nd)
#pragma unroll
      for (int r = 0; r < 4; ++r)
        Og[(size_t)(q0w + mt * 16 + quad * 4 + r) * 128 + nd * 16 + l15] =
            f2bf(acc[mt][nd][r] * inv[mt][r]);
}

// ---------------- launcher ----------------
extern "C" void kernel_launch(void* const* d_in, const int* in_sizes, int n_in,
                              void* d_out, int out_size, void* d_ws, size_t ws_size,
                              hipStream_t stream) {
  const float* X    = (const float*)d_in[0];
  const int*   mask = (const int*)d_in[1];
  const float* W_q  = (const float*)d_in[2];
  const float* W_k  = (const float*)d_in[3];
  const float* W_v  = (const float*)d_in[4];
  const float* W_qm = (const float*)d_in[5];
  const float* W_km = (const float*)d_in[6];
  const float* W_vm = (const float*)d_in[7];
  const float* W_o  = (const float*)d_in[8];
  float* out = (float*)d_out;

  char* ws = (char*)d_ws;
  const size_t MB = 1ull << 20;
  u16* Xb    = (u16*)(ws);
  u16* Wc0   = (u16*)(ws + 16 * MB);
  u16* Wc1   = (u16*)(ws + 24 * MB);
  u16* Wc2   = (u16*)(ws + 32 * MB);
  u16* WmT0  = (u16*)(ws + 40 * MB);
  u16* WmT1  = (u16*)(ws + 48 * MB);
  u16* WmT2  = (u16*)(ws + 56 * MB);
  u16* WqqT0 = (u16*)(ws + 64 * MB);
  u16* WqqT1 = (u16*)(ws + 72 * MB);
  u16* WqqT2 = (u16*)(ws + 80 * MB);
  u16* Qm    = (u16*)(ws + 88 * MB);
  u16* Km    = (u16*)(ws + 104 * MB);
  u16* Vm    = (u16*)(ws + 120 * MB);
  u16* VT    = Wc0;
  u16* AO    = WmT0;
  u16* WoT   = WqqT0;

  static bool attr_done = false;
  if (!attr_done) {
    (void)hipFuncSetAttribute(reinterpret_cast<const void*>(&gemm8<false>),
                              hipFuncAttributeMaxDynamicSharedMemorySize, 131072);
    (void)hipFuncSetAttribute(reinterpret_cast<const void*>(&gemm8<true>),
                              hipFuncAttributeMaxDynamicSharedMemorySize, 131072);
    (void)hipFuncSetAttribute(reinterpret_cast<const void*>(&flash_attn),
                              hipFuncAttributeMaxDynamicSharedMemorySize, 102400);
    attr_done = true;
  }

  // fused prep: X cast, W_{q,k,v} cast, W_{qm,km,vm} transpose
  {
    PrepArgs a;
    a.X = X; a.Xb = Xb;
    a.Wsrc[0] = W_q;  a.Wsrc[1] = W_k;  a.Wsrc[2] = W_v;
    a.Wdst[0] = Wc0;  a.Wdst[1] = Wc1;  a.Wdst[2] = Wc2;
    a.Tsrc[0] = W_qm; a.Tsrc[1] = W_km; a.Tsrc[2] = W_vm;
    a.Tdst[0] = WmT0; a.Tdst[1] = WmT1; a.Tdst[2] = WmT2;
    prep<<<dim3(32768), dim3(256), 0, stream>>>(a);
  }

  // fused weights: WqqT[n][k] = (W_q @ W_qm)^T = WmT . Wc^T   (2048^3, z=3)
  {
    GemmArgs g{{WmT0, WmT1, WmT2}, {Wc0, Wc1, Wc2}, {WqqT0, WqqT1, WqqT2}};
    gemm8<false><<<dim3(8, 8, 3), dim3(512), 131072, stream>>>(g, 2048, 2048, 2048);
  }

  // {Qm,Km,Vm} = Xb . WqqT^T   (4096x2048x2048, z=3)
  {
    GemmArgs g{{Xb, Xb, Xb}, {WqqT0, WqqT1, WqqT2}, {Qm, Km, Vm}};
    gemm8<false><<<dim3(8, 16, 3), dim3(512), 131072, stream>>>(g, 4096, 2048, 2048);
  }

  // fused: Vm slab transpose -> VT, W_o transpose -> WoT
  post_transpose<<<dim3(12288), dim3(256), 0, stream>>>(Vm, VT, W_o, WoT);

  // flash attention: 256 blocks (exact 1/CU), 8 waves, dbuf K/V
  flash_attn<<<dim3(8, 16, 2), dim3(512), 102400, stream>>>(Qm, Km, VT, mask, AO);

  // out = AO . WoT^T   (4096x2048x2048)
  {
    GemmArgs g{{AO, AO, AO}, {WoT, WoT, WoT}, {out, out, out}};
    gemm8<true><<<dim3(8, 16, 1), dim3(512), 131072, stream>>>(g, 4096, 2048, 2048);
  }
}

// Round 5
// 549.634 us; speedup vs baseline: 1.1981x; 1.0024x over previous
//
#include <hip/hip_runtime.h>
#include <hip/hip_bf16.h>

typedef __bf16 bf16x8 __attribute__((ext_vector_type(8)));
typedef float f32x4 __attribute__((ext_vector_type(4)));
typedef unsigned short u16;

__device__ __forceinline__ u16 f2bf(float f) {
  __bf16 b = (__bf16)f;                 // RNE fptrunc
  return __builtin_bit_cast(u16, b);
}
__device__ __forceinline__ float bf2f(u16 v) {
  unsigned int u = ((unsigned int)v) << 16;
  return __builtin_bit_cast(float, u);
}

// ---------------- fused prep: X cast + W_{q,k,v} cast + W_{qm,km,vm} transpose ----------
struct PrepArgs {
  const float* X; u16* Xb;
  const float* Wsrc[3]; u16* Wdst[3];
  const float* Tsrc[3]; u16* Tdst[3];
};

__global__ void prep(PrepArgs a) {
  __shared__ float t[32][33];
  const int blk = blockIdx.x, tid = threadIdx.x;
  if (blk < 8192) {
    int i = blk * 256 + tid;
    float4 f = reinterpret_cast<const float4*>(a.X)[i];
    ushort4 o;
    o.x = f2bf(f.x); o.y = f2bf(f.y); o.z = f2bf(f.z); o.w = f2bf(f.w);
    reinterpret_cast<ushort4*>(a.Xb)[i] = o;
  } else if (blk < 20480) {
    int r = blk - 8192;
    int z = r >> 12;
    int i = (r & 4095) * 256 + tid;
    float4 f = reinterpret_cast<const float4*>(a.Wsrc[z])[i];
    ushort4 o;
    o.x = f2bf(f.x); o.y = f2bf(f.y); o.z = f2bf(f.z); o.w = f2bf(f.w);
    reinterpret_cast<ushort4*>(a.Wdst[z])[i] = o;
  } else {
    int r = blk - 20480;
    int z = r >> 12;
    int rem = r & 4095;
    int bx = rem & 63, by = rem >> 6;
    const float* src = a.Tsrc[z];
    u16* dst = a.Tdst[z];
    int tx = tid & 31, ty = tid >> 5;
#pragma unroll
    for (int i = 0; i < 4; ++i)
      t[ty + i * 8][tx] = src[(size_t)(by * 32 + ty + i * 8) * 2048 + bx * 32 + tx];
    __syncthreads();
#pragma unroll
    for (int i = 0; i < 4; ++i)
      dst[(size_t)(bx * 32 + ty + i * 8) * 2048 + by * 32 + tx] = f2bf(t[tx][ty + i * 8]);
  }
}

// ---------------- fused post-transpose: Vm slab transpose + W_o transpose+cast ----------
__global__ void post_transpose(const u16* __restrict__ Vm, u16* __restrict__ VT,
                               const float* __restrict__ Wo, u16* __restrict__ WoT) {
  __shared__ u16 ts[32][33];
  __shared__ float tf[32][33];
  const int blk = blockIdx.x, tid = threadIdx.x;
  const int tx = tid & 31, ty = tid >> 5;
  if (blk < 8192) {
    int slab = blk >> 8;
    int rem = blk & 255;
    int bx = rem & 63, by = rem >> 6;
    const u16* s = Vm + (size_t)slab * 2048 * 128;
    u16* d = VT + (size_t)slab * 128 * 2048;
#pragma unroll
    for (int i = 0; i < 4; ++i)
      ts[ty + i * 8][tx] = s[(size_t)(bx * 32 + ty + i * 8) * 128 + by * 32 + tx];
    __syncthreads();
#pragma unroll
    for (int i = 0; i < 4; ++i)
      d[(size_t)(by * 32 + ty + i * 8) * 2048 + bx * 32 + tx] = ts[tx][ty + i * 8];
  } else {
    int rem = blk - 8192;
    int bx = rem & 63, by = rem >> 6;
#pragma unroll
    for (int i = 0; i < 4; ++i)
      tf[ty + i * 8][tx] = Wo[(size_t)(by * 32 + ty + i * 8) * 2048 + bx * 32 + tx];
    __syncthreads();
#pragma unroll
    for (int i = 0; i < 4; ++i)
      WoT[(size_t)(bx * 32 + ty + i * 8) * 2048 + by * 32 + tx] = f2bf(tf[tx][ty + i * 8]);
  }
}

// ---------------- shared GEMM helpers ----------------
struct GemmArgs { const u16* A[3]; const u16* B[3]; void* C[3]; };

#define SBARF() do { __builtin_amdgcn_sched_barrier(0); __builtin_amdgcn_s_barrier(); \
                     __builtin_amdgcn_sched_barrier(0); } while (0)
#define LGKM0() do { asm volatile("s_waitcnt lgkmcnt(0)" ::: "memory"); \
                     __builtin_amdgcn_sched_barrier(0); } while (0)
#define LGKM8() do { asm volatile("s_waitcnt lgkmcnt(8)" ::: "memory"); \
                     __builtin_amdgcn_sched_barrier(0); } while (0)
#define VMC4()  do { asm volatile("s_waitcnt vmcnt(4)" ::: "memory"); \
                     __builtin_amdgcn_sched_barrier(0); } while (0)
#define VMC0()  do { asm volatile("s_waitcnt vmcnt(0)" ::: "memory"); \
                     __builtin_amdgcn_sched_barrier(0); } while (0)

__device__ __forceinline__ void gll16(const u16* gp, u16* lp) {
  __builtin_amdgcn_global_load_lds((const __attribute__((address_space(1))) void*)gp,
                                   (__attribute__((address_space(3))) void*)lp, 16, 0, 0);
}

#define MQUAD(A0_, A1_, M0_, M1_) do { \
    __builtin_amdgcn_s_setprio(1); \
    _Pragma("unroll") for (int s_ = 0; s_ < 2; ++s_) \
      _Pragma("unroll") for (int nt = 0; nt < 4; ++nt) { \
        acc[M0_][nt] = __builtin_amdgcn_mfma_f32_16x16x32_bf16(A0_[s_], bF[nt][s_], acc[M0_][nt], 0, 0, 0); \
        acc[M1_][nt] = __builtin_amdgcn_mfma_f32_16x16x32_bf16(A1_[s_], bF[nt][s_], acc[M1_][nt], 0, 0, 0); } \
    __builtin_amdgcn_s_setprio(0); \
    __builtin_amdgcn_sched_barrier(0); \
  } while (0)

// ---------------- 256x256 8-phase bf16 MFMA GEMM (R5: m201-faithful read/stage map) ---
// 512 threads = 8 waves (2M x 4N), per-wave 128x64, BK=64, 128 KiB LDS (2 dbuf).
// R5 change vs R4: ds_reads distributed 12/4/4/4 per half-iteration (m201 template)
// instead of 12/12/0/0 — each phase reads exactly the A-quadrant its MFMA consumes.
// New stage-slot map (forced by overwrite-safety: buf A-regions are read ph1-4/ph5-8):
//   s1(ph1): buf1 A h0 <- tile to      s5(ph5): buf0 A h0 <- te+2
//   s2(ph2): buf1 A h1 <- tile to      s6(ph6): buf0 A h1 <- te+2
//   s3(ph3): buf0 B h0 <- te+2        s7(ph7): buf1 B h0 <- to+2
//   s4(ph4): buf0 B h1 <- te+2        s8(ph8): buf1 B h1 <- to+2
// vmcnt(4) after ph4's MFMA: newest 2 halves (s3,s4) may remain in flight -> forces
// s1,s2 landed -> buf1 (to) complete before ph5 reads it. vmcnt(4) after ph8: newest
// s7,s8 in flight -> forces s3..s6 landed -> buf0 (te+2) complete before next ph1.
// Overwrite windows: buf0-B written ph3/4 (last read ph1-end), buf0-A written ph5/6
// (last read ph4-end), buf1-B written ph7/8 (last read ph5-end), buf1-A written
// next ph1/2 (last read ph8-end). All separated by >=1 full barrier. Last iteration:
// s3..s8 skipped, ph4 uses vmcnt(0) to guarantee s1,s2 landed.
template <bool F32OUT>
__global__ __launch_bounds__(512, 2)
void gemm8(GemmArgs g, int M, int N, int K) {
  (void)M;
  extern __shared__ u16 lds[];
  const u16* A = g.A[blockIdx.z];
  const u16* B = g.B[blockIdx.z];
  const int tid = threadIdx.x;
  const int lane = tid & 63, w = tid >> 6;          // 8 waves
  const int wm = w >> 2, wn = w & 3;                // 2M x 4N wave grid
  const int l15 = lane & 15, quad = lane >> 4;
  const int m0 = blockIdx.y * 256, n0 = blockIdx.x * 256;

  const int srow = tid & 127;
  const int sks8 = (tid >> 7) * 8;
  const int swu = w * 512;

  auto stage = [&](int buf, int mat, int half, int kt) {
    const u16* src = mat ? B : A;
    const size_t g0 = (size_t)((mat ? n0 : m0) + half * 128 + srow) * K
                    + (size_t)kt * 64 + sks8;
    u16* l0 = lds + buf * 32768 + (mat * 2 + half) * 8192 + swu;
    gll16(src + g0, l0);
    gll16(src + g0 + 32, l0 + 4096);
  };

  const int aoff = wm * 8192 + quad * 1024 + l15 * 8;
  const int boff = 16384 + (wn >> 1) * 8192 + quad * 1024 + ((wn & 1) * 64 + l15) * 8;

  const f32x4 zf = {0.f, 0.f, 0.f, 0.f};
  f32x4 acc[8][4];
#pragma unroll
  for (int i = 0; i < 8; ++i)
#pragma unroll
    for (int j = 0; j < 4; ++j) acc[i][j] = zf;

  bf16x8 aA[2][2], bF[4][2];

#define LDB_ALL8(buf_) do { _Pragma("unroll") for (int nt = 0; nt < 4; ++nt) { \
    const u16* p_ = lds + (buf_) * 32768 + boff + nt * 128; \
    bF[nt][0] = *reinterpret_cast<const bf16x8*>(p_); \
    bF[nt][1] = *reinterpret_cast<const bf16x8*>(p_ + 4096); } } while (0)
#define LDA_PAIR(buf_, mb_) do { _Pragma("unroll") for (int mi = 0; mi < 2; ++mi) { \
    const u16* p_ = lds + (buf_) * 32768 + aoff + ((mb_) + mi) * 128; \
    aA[mi][0] = *reinterpret_cast<const bf16x8*>(p_); \
    aA[mi][1] = *reinterpret_cast<const bf16x8*>(p_ + 4096); } } while (0)

  const int NT = K >> 6;
  const int NI = NT >> 1;

  // prologue: tile0 all 4 halves -> buf0; tile1 B halves -> buf1 (tile1 A comes via
  // iter0's s1/s2). vmcnt(4): newest 4 loads = buf1-B may fly; buf0 complete.
  stage(0, 1, 0, 0); stage(0, 1, 1, 0); stage(0, 0, 0, 0); stage(0, 0, 1, 0);
  stage(1, 1, 0, 1); stage(1, 1, 1, 1);
  VMC4();
  SBARF();

  for (int i = 0; i < NI; ++i) {
    const int te = 2 * i, to = te + 1;
    const bool pf = (te + 2 < NT);
    // phase 1: B(all)+A[m0,m1] of buf0; s1: buf1 A h0 (tile to)
    LDB_ALL8(0); LDA_PAIR(0, 0);
    stage(1, 0, 0, to);
    LGKM8(); SBARF(); LGKM0();
    MQUAD(aA[0], aA[1], 0, 1);
    SBARF();
    // phase 2: A[m2,m3]; s2: buf1 A h1 (tile to)
    LDA_PAIR(0, 2);
    stage(1, 0, 1, to);
    SBARF(); LGKM0();
    MQUAD(aA[0], aA[1], 2, 3);
    SBARF();
    // phase 3: A[m4,m5]; s3: buf0 B h0 (te+2)
    LDA_PAIR(0, 4);
    if (pf) stage(0, 1, 0, te + 2);
    SBARF(); LGKM0();
    MQUAD(aA[0], aA[1], 4, 5);
    SBARF();
    // phase 4: A[m6,m7]; s4: buf0 B h1 (te+2); vmcnt -> buf1(to) complete
    LDA_PAIR(0, 6);
    if (pf) stage(0, 1, 1, te + 2);
    SBARF(); LGKM0();
    MQUAD(aA[0], aA[1], 6, 7);
    if (pf) { VMC4(); } else { VMC0(); }
    SBARF();
    // phase 5: B(all)+A[m0,m1] of buf1; s5: buf0 A h0 (te+2)
    LDB_ALL8(1); LDA_PAIR(1, 0);
    if (pf) stage(0, 0, 0, te + 2);
    LGKM8(); SBARF(); LGKM0();
    MQUAD(aA[0], aA[1], 0, 1);
    SBARF();
    // phase 6: A[m2,m3]; s6: buf0 A h1 (te+2)
    LDA_PAIR(1, 2);
    if (pf) stage(0, 0, 1, te + 2);
    SBARF(); LGKM0();
    MQUAD(aA[0], aA[1], 2, 3);
    SBARF();
    // phase 7: A[m4,m5]; s7: buf1 B h0 (to+2)
    LDA_PAIR(1, 4);
    if (pf) stage(1, 1, 0, to + 2);
    SBARF(); LGKM0();
    MQUAD(aA[0], aA[1], 4, 5);
    SBARF();
    // phase 8: A[m6,m7]; s8: buf1 B h1 (to+2); vmcnt -> buf0(te+2) complete
    LDA_PAIR(1, 6);
    if (pf) stage(1, 1, 1, to + 2);
    SBARF(); LGKM0();
    MQUAD(aA[0], aA[1], 6, 7);
    VMC4();
    SBARF();
  }

#pragma unroll
  for (int mt = 0; mt < 8; ++mt)
#pragma unroll
    for (int nt = 0; nt < 4; ++nt)
#pragma unroll
      for (int r = 0; r < 4; ++r) {
        int mrow = m0 + wm * 128 + mt * 16 + quad * 4 + r;
        int ncol = n0 + wn * 64 + nt * 16 + l15;
        if constexpr (F32OUT)
          ((float*)g.C[blockIdx.z])[(size_t)mrow * N + ncol] = acc[mt][nt][r];
        else
          ((u16*)g.C[blockIdx.z])[(size_t)mrow * N + ncol] = f2bf(acc[mt][nt][r]);
      }
#undef LDB_ALL8
#undef LDA_PAIR
}

// ---------------- flash attention R5: R4 structure + T5 setprio on MFMA clusters ------
__global__ __launch_bounds__(512, 2)
void flash_attn(const u16* __restrict__ Qm, const u16* __restrict__ Km,
                const u16* __restrict__ VTr, const int* __restrict__ mask,
                u16* __restrict__ Out) {
  extern __shared__ u16 lds[];
  const int b = blockIdx.z, head = blockIdx.y, qb = blockIdx.x;
  const int slab = b * 16 + head;
  const u16* Qs = Qm + (size_t)slab * 2048 * 128;
  const u16* Kg = Km + (size_t)slab * 2048 * 128;
  const u16* Vg = VTr + (size_t)slab * 128 * 2048;
  u16* Og = Out + (size_t)slab * 2048 * 128;
  const int* mb = mask + b * 2048;

  const int tid = threadIdx.x;
  const int lane = tid & 63, w = tid >> 6;          // 8 waves
  const int l15 = lane & 15, quad = lane >> 4;
  const int q0w = qb * 256 + w * 32;

  u16* Mf = lds + 49152;
  u16* PLw = lds + 32768 + w * 2048;

#pragma unroll
  for (int j = 0; j < 4; ++j) {
    int i = j * 512 + tid;
    Mf[i] = mb[i] ? (u16)0x3F80 : (u16)0;
  }

  bf16x8 aQ[2][4];
#pragma unroll
  for (int mt = 0; mt < 2; ++mt)
#pragma unroll
    for (int c = 0; c < 4; ++c)
      aQ[mt][c] = *reinterpret_cast<const bf16x8*>(
          Qs + (size_t)(q0w + mt * 16 + l15) * 128 + c * 32 + quad * 8);

  int mq[2][4];
#pragma unroll
  for (int mt = 0; mt < 2; ++mt)
#pragma unroll
    for (int r = 0; r < 4; ++r) mq[mt][r] = mb[q0w + mt * 16 + quad * 4 + r];

  auto stageKV = [&](int buf, int k0) {
#pragma unroll
    for (int t = 0; t < 4; ++t) {
      int idx = w * 4 + t;              // 0..31 (wave-uniform)
      if (idx < 16) {                   // K: dchunk = idx
        const u16* gp = Kg + (size_t)(k0 + lane) * 128 + idx * 8;
        gll16(gp, lds + buf * 8192 + idx * 512);
      } else {                          // V: kchunk = (idx-16)>>1, d-half = (idx-16)&1
        int u = idx - 16, kc = u >> 1, dh = u & 1;
        const u16* gp = Vg + (size_t)(dh * 64 + lane) * 2048 + k0 + kc * 8;
        gll16(gp, lds + 16384 + buf * 8192 + (kc * 128 + dh * 64) * 8);
      }
    }
  };

  const f32x4 zf = {0.f, 0.f, 0.f, 0.f};
  float l_part[2][4];
  f32x4 acc[2][8];
#pragma unroll
  for (int mt = 0; mt < 2; ++mt) {
#pragma unroll
    for (int r = 0; r < 4; ++r) l_part[mt][r] = 0.f;
#pragma unroll
    for (int nd = 0; nd < 8; ++nd) acc[mt][nd] = zf;
  }

  stageKV(0, 0);
  __syncthreads();

  for (int t = 0; t < 32; ++t) {
    const int cur = t & 1;
    const int k0 = t * 64;
    if (t + 1 < 32) stageKV(cur ^ 1, k0 + 64);

    const u16* Ks = lds + cur * 8192;
    const u16* Vs = lds + 16384 + cur * 8192;

    // S[32q x 64k] = Q . K^T
    f32x4 st[2][4];
#pragma unroll
    for (int mt = 0; mt < 2; ++mt)
#pragma unroll
      for (int nt = 0; nt < 4; ++nt) st[mt][nt] = zf;
    __builtin_amdgcn_s_setprio(1);
#pragma unroll
    for (int c = 0; c < 4; ++c)
#pragma unroll
      for (int nt = 0; nt < 4; ++nt) {
        bf16x8 bK = *reinterpret_cast<const bf16x8*>(
            &Ks[((c * 4 + quad) * 64 + nt * 16 + l15) * 8]);
        st[0][nt] = __builtin_amdgcn_mfma_f32_16x16x32_bf16(aQ[0][c], bK, st[0][nt], 0, 0, 0);
        st[1][nt] = __builtin_amdgcn_mfma_f32_16x16x32_bf16(aQ[1][c], bK, st[1][nt], 0, 0, 0);
      }
    __builtin_amdgcn_s_setprio(0);

    // no-max softmax: p = mq ? exp(s)*mk : 1   (exact vs reference semantics)
    float mkf[4];
#pragma unroll
    for (int nt = 0; nt < 4; ++nt) mkf[nt] = bf2f(Mf[k0 + nt * 16 + l15]);

#pragma unroll
    for (int mt = 0; mt < 2; ++mt)
#pragma unroll
      for (int nt = 0; nt < 4; ++nt)
#pragma unroll
        for (int r = 0; r < 4; ++r) {
          float e = __expf(st[mt][nt][r]) * mkf[nt];
          float p = mq[mt][r] ? e : 1.0f;
          l_part[mt][r] += p;
          int row = mt * 16 + quad * 4 + r;
          int col = nt * 16 + l15;
          int addr = row * 64 + (((col >> 3) ^ (row & 7)) << 3) + (col & 7);
          PLw[addr] = f2bf(p);
        }

    // O += P . V
    __builtin_amdgcn_s_setprio(1);
#pragma unroll
    for (int pc = 0; pc < 2; ++pc) {
      bf16x8 aP0 = *reinterpret_cast<const bf16x8*>(
          &PLw[(0 + l15) * 64 + (((pc * 4 + quad) ^ (l15 & 7)) << 3)]);
      bf16x8 aP1 = *reinterpret_cast<const bf16x8*>(
          &PLw[(16 + l15) * 64 + (((pc * 4 + quad) ^ (l15 & 7)) << 3)]);
#pragma unroll
      for (int nd = 0; nd < 8; ++nd) {
        bf16x8 bV = *reinterpret_cast<const bf16x8*>(
            &Vs[((pc * 4 + quad) * 128 + nd * 16 + l15) * 8]);
        acc[0][nd] = __builtin_amdgcn_mfma_f32_16x16x32_bf16(aP0, bV, acc[0][nd], 0, 0, 0);
        acc[1][nd] = __builtin_amdgcn_mfma_f32_16x16x32_bf16(aP1, bV, acc[1][nd], 0, 0, 0);
      }
    }
    __builtin_amdgcn_s_setprio(0);

    VMC0();
    SBARF();
  }

  float inv[2][4];
#pragma unroll
  for (int mt = 0; mt < 2; ++mt)
#pragma unroll
    for (int r = 0; r < 4; ++r) {
      float l = l_part[mt][r];
      l += __shfl_xor(l, 1, 16);
      l += __shfl_xor(l, 2, 16);
      l += __shfl_xor(l, 4, 16);
      l += __shfl_xor(l, 8, 16);
      inv[mt][r] = 1.0f / l;
    }
#pragma unroll
  for (int mt = 0; mt < 2; ++mt)
#pragma unroll
    for (int nd = 0; nd < 8; ++nd)
#pragma unroll
      for (int r = 0; r < 4; ++r)
        Og[(size_t)(q0w + mt * 16 + quad * 4 + r) * 128 + nd * 16 + l15] =
            f2bf(acc[mt][nd][r] * inv[mt][r]);
}

// ---------------- launcher ----------------
extern "C" void kernel_launch(void* const* d_in, const int* in_sizes, int n_in,
                              void* d_out, int out_size, void* d_ws, size_t ws_size,
                              hipStream_t stream) {
  const float* X    = (const float*)d_in[0];
  const int*   mask = (const int*)d_in[1];
  const float* W_q  = (const float*)d_in[2];
  const float* W_k  = (const float*)d_in[3];
  const float* W_v  = (const float*)d_in[4];
  const float* W_qm = (const float*)d_in[5];
  const float* W_km = (const float*)d_in[6];
  const float* W_vm = (const float*)d_in[7];
  const float* W_o  = (const float*)d_in[8];
  float* out = (float*)d_out;

  char* ws = (char*)d_ws;
  const size_t MB = 1ull << 20;
  u16* Xb    = (u16*)(ws);
  u16* Wc0   = (u16*)(ws + 16 * MB);
  u16* Wc1   = (u16*)(ws + 24 * MB);
  u16* Wc2   = (u16*)(ws + 32 * MB);
  u16* WmT0  = (u16*)(ws + 40 * MB);
  u16* WmT1  = (u16*)(ws + 48 * MB);
  u16* WmT2  = (u16*)(ws + 56 * MB);
  u16* WqqT0 = (u16*)(ws + 64 * MB);
  u16* WqqT1 = (u16*)(ws + 72 * MB);
  u16* WqqT2 = (u16*)(ws + 80 * MB);
  u16* Qm    = (u16*)(ws + 88 * MB);
  u16* Km    = (u16*)(ws + 104 * MB);
  u16* Vm    = (u16*)(ws + 120 * MB);
  u16* VT    = Wc0;
  u16* AO    = WmT0;
  u16* WoT   = WqqT0;

  static bool attr_done = false;
  if (!attr_done) {
    (void)hipFuncSetAttribute(reinterpret_cast<const void*>(&gemm8<false>),
                              hipFuncAttributeMaxDynamicSharedMemorySize, 131072);
    (void)hipFuncSetAttribute(reinterpret_cast<const void*>(&gemm8<true>),
                              hipFuncAttributeMaxDynamicSharedMemorySize, 131072);
    (void)hipFuncSetAttribute(reinterpret_cast<const void*>(&flash_attn),
                              hipFuncAttributeMaxDynamicSharedMemorySize, 102400);
    attr_done = true;
  }

  // fused prep: X cast, W_{q,k,v} cast, W_{qm,km,vm} transpose
  {
    PrepArgs a;
    a.X = X; a.Xb = Xb;
    a.Wsrc[0] = W_q;  a.Wsrc[1] = W_k;  a.Wsrc[2] = W_v;
    a.Wdst[0] = Wc0;  a.Wdst[1] = Wc1;  a.Wdst[2] = Wc2;
    a.Tsrc[0] = W_qm; a.Tsrc[1] = W_km; a.Tsrc[2] = W_vm;
    a.Tdst[0] = WmT0; a.Tdst[1] = WmT1; a.Tdst[2] = WmT2;
    prep<<<dim3(32768), dim3(256), 0, stream>>>(a);
  }

  // fused weights: WqqT[n][k] = (W_q @ W_qm)^T = WmT . Wc^T   (2048^3, z=3)
  {
    GemmArgs g{{WmT0, WmT1, WmT2}, {Wc0, Wc1, Wc2}, {WqqT0, WqqT1, WqqT2}};
    gemm8<false><<<dim3(8, 8, 3), dim3(512), 131072, stream>>>(g, 2048, 2048, 2048);
  }

  // {Qm,Km,Vm} = Xb . WqqT^T   (4096x2048x2048, z=3)
  {
    GemmArgs g{{Xb, Xb, Xb}, {WqqT0, WqqT1, WqqT2}, {Qm, Km, Vm}};
    gemm8<false><<<dim3(8, 16, 3), dim3(512), 131072, stream>>>(g, 4096, 2048, 2048);
  }

  // fused: Vm slab transpose -> VT, W_o transpose -> WoT
  post_transpose<<<dim3(12288), dim3(256), 0, stream>>>(Vm, VT, W_o, WoT);

  // flash attention: 256 blocks (exact 1/CU), 8 waves, dbuf K/V
  flash_attn<<<dim3(8, 16, 2), dim3(512), 102400, stream>>>(Qm, Km, VT, mask, AO);

  // out = AO . WoT^T   (4096x2048x2048)
  {
    GemmArgs g{{AO, AO, AO}, {WoT, WoT, WoT}, {out, out, out}};
    gemm8<true><<<dim3(8, 16, 1), dim3(512), 131072, stream>>>(g, 4096, 2048, 2048);
  }
}